// Round 1
// baseline (512.316 us; speedup 1.0000x reference)
//
#include <hip/hip_runtime.h>

// B=128, K=1024 pairwise-distance adjacency + row softmax.
// Single pass: one wave per output row; row (1024 fp32) lives in 16 VGPRs.
// Row max of exp(-d*p) is exactly 1.0 (diagonal d_ii == 0 when computed
// directly as (xi-xj)^2), so softmax uses a constant shift -> no max pass.

#define K_PTS 1024
#define ROWS_PER_BLOCK 4   // 256 threads = 4 waves, one row per wave

__global__ __launch_bounds__(256) void adj_softmax_kernel(
    const float* __restrict__ coords,   // [B, K, 3]
    const float* __restrict__ prec,     // [1]
    float* __restrict__ out,            // [B, K, K]
    int B) {
  __shared__ float sx[K_PTS];
  __shared__ float sy[K_PTS];
  __shared__ float sz[K_PTS];

  const int tid  = threadIdx.x;
  const int lane = tid & 63;
  const int wave = tid >> 6;
  const int tilesPerBatch = K_PTS / ROWS_PER_BLOCK;      // 256
  const int b    = blockIdx.x / tilesPerBatch;
  const int tile = blockIdx.x % tilesPerBatch;

  const float p = prec[0];

  // ---- stage this batch's coords into LDS, deinterleaved (x|y|z) ----
  // 1024 points * 3 floats = 3072 floats = 768 float4; 3 float4 per thread.
  {
    const float* cb = coords + (size_t)b * (K_PTS * 3);
    const int p0 = tid * 4;                       // 4 points per thread
    const float4* src = (const float4*)(cb + (size_t)p0 * 3);
    float4 a0 = src[0];   // {x0,y0,z0,x1}
    float4 a1 = src[1];   // {y1,z1,x2,y2}
    float4 a2 = src[2];   // {z2,x3,y3,z3}
    sx[p0 + 0] = a0.x; sy[p0 + 0] = a0.y; sz[p0 + 0] = a0.z;
    sx[p0 + 1] = a0.w; sy[p0 + 1] = a1.x; sz[p0 + 1] = a1.y;
    sx[p0 + 2] = a1.z; sy[p0 + 2] = a1.w; sz[p0 + 2] = a2.x;
    sx[p0 + 3] = a2.y; sy[p0 + 3] = a2.z; sz[p0 + 3] = a2.w;
  }
  __syncthreads();

  const int i = tile * ROWS_PER_BLOCK + wave;     // this wave's row
  const float xi = sx[i];
  const float yi = sy[i];
  const float zi = sz[i];

  float4 e[4];
  float acc = 0.0f;

#pragma unroll
  for (int t = 0; t < 4; ++t) {
    const int j0 = 4 * lane + 256 * t;            // 4 consecutive points
    float4 vx = *(const float4*)&sx[j0];          // ds_read_b128, conflict-free
    float4 vy = *(const float4*)&sy[j0];
    float4 vz = *(const float4*)&sz[j0];

    float dx, dy, dz, d, xv;
    float4 ev;

    dx = vx.x - xi; dy = vy.x - yi; dz = vz.x - zi;
    d  = fmaf(dx, dx, fmaf(dy, dy, dz * dz));
    xv = __expf(-p * d);
    ev.x = __expf(xv - 1.0f);

    dx = vx.y - xi; dy = vy.y - yi; dz = vz.y - zi;
    d  = fmaf(dx, dx, fmaf(dy, dy, dz * dz));
    xv = __expf(-p * d);
    ev.y = __expf(xv - 1.0f);

    dx = vx.z - xi; dy = vy.z - yi; dz = vz.z - zi;
    d  = fmaf(dx, dx, fmaf(dy, dy, dz * dz));
    xv = __expf(-p * d);
    ev.z = __expf(xv - 1.0f);

    dx = vx.w - xi; dy = vy.w - yi; dz = vz.w - zi;
    d  = fmaf(dx, dx, fmaf(dy, dy, dz * dz));
    xv = __expf(-p * d);
    ev.w = __expf(xv - 1.0f);

    e[t] = ev;
    acc += (ev.x + ev.y) + (ev.z + ev.w);
  }

  // ---- wave-level reduction (64 lanes) for the softmax denominator ----
#pragma unroll
  for (int off = 32; off > 0; off >>= 1) {
    acc += __shfl_xor(acc, off, 64);
  }
  const float inv = 1.0f / acc;

  // ---- normalized, coalesced float4 stores: row written exactly once ----
  float* orow = out + ((size_t)b * K_PTS + i) * K_PTS;
#pragma unroll
  for (int t = 0; t < 4; ++t) {
    float4 ev = e[t];
    ev.x *= inv; ev.y *= inv; ev.z *= inv; ev.w *= inv;
    *(float4*)&orow[4 * lane + 256 * t] = ev;
  }
}

extern "C" void kernel_launch(void* const* d_in, const int* in_sizes, int n_in,
                              void* d_out, int out_size, void* d_ws, size_t ws_size,
                              hipStream_t stream) {
  const float* coords = (const float*)d_in[0];   // [B, K, 3] fp32
  const float* prec   = (const float*)d_in[1];   // [1] fp32
  float* out = (float*)d_out;                    // [B, K, K] fp32

  const int B = in_sizes[0] / (K_PTS * 3);       // 128
  const int grid = B * (K_PTS / ROWS_PER_BLOCK); // 128 * 256 = 32768 blocks

  adj_softmax_kernel<<<grid, 256, 0, stream>>>(coords, prec, out, B);
}